// Round 1
// baseline (362.335 us; speedup 1.0000x reference)
//
#include <hip/hip_runtime.h>

#define NNODES 50000
#define NFEAT 256
#define NHID 32
#define NHEADS 8
#define NCLASSES 32
#define NEDGES 800000
#define ETOT (NEDGES + NNODES)   // 850000 with self loops
#define NSCAN_BLK 196            // ceil(50000/256)
#define GEMM1_BLKS 782           // ceil(50000/64)
#define SCAT_BLKS 3321           // ceil(850000/256)
#define AGG1_BLKS 100000         // 12500 dst-blocks * 8 head slices

typedef __attribute__((ext_vector_type(8))) short short8;
typedef __attribute__((ext_vector_type(4))) float f32x4;

__device__ __forceinline__ void get_edge(const int* __restrict__ ei, int e,
                                         int& s, int& d) {
    if (e < NEDGES) { s = ei[e]; d = ei[NEDGES + e]; }
    else            { s = e - NEDGES; d = s; }
}
__device__ __forceinline__ float lrelu(float x) { return x > 0.f ? x : 0.2f * x; }
__device__ __forceinline__ unsigned short f2bf(float f) {   // RNE
    unsigned u = __float_as_uint(f);
    unsigned r = u + 0x7fffu + ((u >> 16) & 1u);
    return (unsigned short)(r >> 16);
}
__device__ __forceinline__ float bflo(unsigned u) { return __uint_as_float(u << 16); }
__device__ __forceinline__ float bfhi(unsigned u) { return __uint_as_float(u & 0xffff0000u); }

// ---------- fused: weight prep (blocks 0..35) + degree histogram + rank (rest) ----------
// pos[e] = within-dst arrival rank, from the SAME atomicAdd that builds the histogram.
__global__ void wprep_hist_k(const float* __restrict__ W1, const float* __restrict__ W2,
                             short8* __restrict__ W1frag, short8* __restrict__ W2frag,
                             const int* __restrict__ ei, int* __restrict__ deg,
                             unsigned short* __restrict__ pos) {
    if (blockIdx.x < 36) {
        int idx = blockIdx.x * 256 + threadIdx.x;
        if (idx < 8192) {
            int kc = idx >> 10, r = idx & 1023;
            int nt = r >> 6, lane = r & 63;
            int l16 = lane & 15, quad = lane >> 4;
            int n = nt * 16 + l16, k0 = kc * 32 + quad * 8;
            short8 v;
#pragma unroll
            for (int j = 0; j < 8; ++j) v[j] = (short)f2bf(W1[(k0 + j) * 256 + n]);
            W1frag[idx] = v;
        } else if (idx < 8192 + 1024) {
            int g = idx - 8192;
            int kc = g >> 7, r = g & 127;
            int nt = r >> 6, lane = r & 63;
            int l16 = lane & 15, quad = lane >> 4;
            int n = nt * 16 + l16, k0 = kc * 32 + quad * 8;
            short8 v;
#pragma unroll
            for (int j = 0; j < 8; ++j) v[j] = (short)f2bf(W2[(k0 + j) * 32 + n]);
            W2frag[g] = v;
        }
    } else {
        int e = (blockIdx.x - 36) * 256 + threadIdx.x;
        if (e >= ETOT) return;
        int d = (e < NEDGES) ? ei[NEDGES + e] : (e - NEDGES);
        pos[e] = (unsigned short)atomicAdd(&deg[d], 1);
    }
}

// ---------- parallel scan, phase 1: per-block exclusive scan + block sums ----------
__global__ void scan_part_k(const int* __restrict__ deg, int* __restrict__ row_local,
                            int* __restrict__ bsum) {
    __shared__ int ws[4];
    int t = threadIdx.x, lane = t & 63, wid = t >> 6;
    int idx = blockIdx.x * 256 + t;
    int v = (idx < NNODES) ? deg[idx] : 0;
    int inc = v;
#pragma unroll
    for (int off = 1; off < 64; off <<= 1) {
        int u = __shfl_up(inc, off, 64);
        if (lane >= off) inc += u;
    }
    if (lane == 63) ws[wid] = inc;
    __syncthreads();
    int woff = 0;
#pragma unroll
    for (int j = 0; j < 4; ++j) woff += (j < wid) ? ws[j] : 0;
    if (idx < NNODES) row_local[idx] = woff + inc - v;
    if (t == 255) bsum[blockIdx.x] = woff + inc;
}

// ---------- scan phase 2+3 merged ----------
__global__ void scan_fix_k(const int* __restrict__ row_local, const int* __restrict__ bsum,
                           int* __restrict__ row_start) {
    __shared__ int ws[4];
    __shared__ int sboff;
    int t = threadIdx.x, lane = t & 63, wid = t >> 6;
    int v = (t < NSCAN_BLK) ? bsum[t] : 0;
    int inc = v;
#pragma unroll
    for (int off = 1; off < 64; off <<= 1) {
        int u = __shfl_up(inc, off, 64);
        if (lane >= off) inc += u;
    }
    if (lane == 63) ws[wid] = inc;
    __syncthreads();
    int woff = 0;
#pragma unroll
    for (int j = 0; j < 4; ++j) woff += (j < wid) ? ws[j] : 0;
    if (t == blockIdx.x) sboff = woff + inc - v;
    __syncthreads();
    int idx = blockIdx.x * 256 + t;
    if (idx < NNODES) row_start[idx] = row_local[idx] + sboff;
    if (idx == 0) row_start[NNODES] = ETOT;
}

// ---------- fused GEMM1 (MFMA bf16) + attn1 epilogue + atomic-free CSR scatter ----------
// z1 stored head-major: z1T[h][node][32] bf16 (64B row per head-slice).
// as/ad stored transposed: asT[h][node], adT[h][node].
__global__ __launch_bounds__(256) void gemm1_scatter_k(
        const float* __restrict__ x, const short8* __restrict__ Wfrag,
        const float* __restrict__ av, const float* __restrict__ bv,
        unsigned short* __restrict__ z1T, float* __restrict__ asT, float* __restrict__ adT,
        const int* __restrict__ ei, const int* __restrict__ row_start,
        const unsigned short* __restrict__ pos, int* __restrict__ csr_src) {
    __shared__ short8 wlds[1024];    // 16 KB: one kc-slice, fragment-ordered
    if (blockIdx.x >= GEMM1_BLKS) {
        int e = (blockIdx.x - GEMM1_BLKS) * 256 + threadIdx.x;
        if (e >= ETOT) return;
        int s, d;
        get_edge(ei, e, s, d);
        csr_src[row_start[d] + (int)pos[e]] = s;    // no atomic: rank precomputed
        return;
    }
    int t = threadIdx.x;
    int w = t >> 6, lane = t & 63;
    int quad = lane >> 4, l16 = lane & 15;
    int mA = blockIdx.x * 64 + w * 16 + l16;
    int mAl = min(mA, NNODES - 1);

    f32x4 acc[16];
#pragma unroll
    for (int nt = 0; nt < 16; ++nt) acc[nt] = (f32x4){0.f, 0.f, 0.f, 0.f};

    short8 pf[4];
#pragma unroll
    for (int j = 0; j < 4; ++j) pf[j] = Wfrag[j * 256 + t];   // kc=0 slice

    for (int kc = 0; kc < 8; ++kc) {
        __syncthreads();
#pragma unroll
        for (int j = 0; j < 4; ++j) wlds[j * 256 + t] = pf[j];
        __syncthreads();
        if (kc < 7) {
#pragma unroll
            for (int j = 0; j < 4; ++j) pf[j] = Wfrag[(kc + 1) * 1024 + j * 256 + t];
        }
        int k0 = kc * 32 + quad * 8;
        const float4* xp = (const float4*)(x + (size_t)mAl * 256 + k0);
        float4 a0 = xp[0], a1 = xp[1];
        short8 af;
        af[0] = (short)f2bf(a0.x); af[1] = (short)f2bf(a0.y);
        af[2] = (short)f2bf(a0.z); af[3] = (short)f2bf(a0.w);
        af[4] = (short)f2bf(a1.x); af[5] = (short)f2bf(a1.y);
        af[6] = (short)f2bf(a1.z); af[7] = (short)f2bf(a1.w);
#pragma unroll
        for (int nt = 0; nt < 16; ++nt) {
            short8 bf8 = wlds[nt * 64 + lane];
            acc[nt] = __builtin_amdgcn_mfma_f32_16x16x32_bf16(af, bf8, acc[nt], 0, 0, 0);
        }
    }
    int mrow0 = blockIdx.x * 64 + w * 16 + quad * 4;
#pragma unroll
    for (int nt = 0; nt < 16; ++nt) {
        int hh = nt >> 1, cc = (nt & 1) * 16 + l16;
#pragma unroll
        for (int r = 0; r < 4; ++r) {
            int mr = mrow0 + r;
            if (mr < NNODES)
                z1T[((size_t)hh * NNODES + mr) * 32 + cc] = f2bf(acc[nt][r]);
        }
    }
#pragma unroll
    for (int h = 0; h < 8; ++h) {
        float av0 = av[(2 * h) * 16 + l16], av1v = av[(2 * h + 1) * 16 + l16];
        float bv0 = bv[(2 * h) * 16 + l16], bv1v = bv[(2 * h + 1) * 16 + l16];
#pragma unroll
        for (int r = 0; r < 4; ++r) {
            float pa = acc[2 * h][r] * av0 + acc[2 * h + 1][r] * av1v;
            float pb = acc[2 * h][r] * bv0 + acc[2 * h + 1][r] * bv1v;
#pragma unroll
            for (int off = 1; off < 16; off <<= 1) {
                pa += __shfl_xor(pa, off, 64);
                pb += __shfl_xor(pb, off, 64);
            }
            int mr = mrow0 + r;
            if (l16 == 0 && mr < NNODES) {
                asT[(size_t)h * NNODES + mr] = pa;
                adT[(size_t)h * NNODES + mr] = pb;
            }
        }
    }
}

// ---------- GEMM2 (MFMA bf16) + fused attn2 epilogue; z2 stored bf16 ----------
__global__ __launch_bounds__(256) void gemm2_mfma_k(
        const unsigned short* __restrict__ h1, const short8* __restrict__ Wfrag,
        const float* __restrict__ av, const float* __restrict__ bv,
        unsigned short* __restrict__ z2b, float* __restrict__ as_, float* __restrict__ ad_) {
    int w = threadIdx.x >> 6, lane = threadIdx.x & 63;
    int quad = lane >> 4, l16 = lane & 15;
    int mA = blockIdx.x * 64 + w * 16 + l16;
    int mAl = min(mA, NNODES - 1);

    f32x4 acc[2];
    acc[0] = (f32x4){0.f, 0.f, 0.f, 0.f};
    acc[1] = (f32x4){0.f, 0.f, 0.f, 0.f};
    for (int kc = 0; kc < 8; ++kc) {
        int k0 = kc * 32 + quad * 8;
        short8 af = *(const short8*)(h1 + (size_t)mAl * 256 + k0);
#pragma unroll
        for (int nt = 0; nt < 2; ++nt) {
            short8 bf8 = Wfrag[kc * 128 + nt * 64 + lane];
            acc[nt] = __builtin_amdgcn_mfma_f32_16x16x32_bf16(af, bf8, acc[nt], 0, 0, 0);
        }
    }
    int mrow0 = blockIdx.x * 64 + w * 16 + quad * 4;
    float av0 = av[l16], av1v = av[16 + l16];
    float bv0 = bv[l16], bv1v = bv[16 + l16];
#pragma unroll
    for (int r = 0; r < 4; ++r) {
        int mr = mrow0 + r;
        float pa = acc[0][r] * av0 + acc[1][r] * av1v;
        float pb = acc[0][r] * bv0 + acc[1][r] * bv1v;
#pragma unroll
        for (int off = 1; off < 16; off <<= 1) {
            pa += __shfl_xor(pa, off, 64);
            pb += __shfl_xor(pb, off, 64);
        }
        if (mr < NNODES) {
            z2b[(size_t)mr * 32 + l16] = f2bf(acc[0][r]);
            z2b[(size_t)mr * 32 + 16 + l16] = f2bf(acc[1][r]);
            if (l16 == 0) { as_[mr] = pa; ad_[mr] = pb; }
        }
    }
}

// ---------- layer-1 aggregation: head-sliced, XCD-affine ----------
// blockIdx.x = dblk*8 + h : round-robin block->XCD dispatch pins head-slice h to XCD h,
// so each XCD's L2 only caches its 3.2MB z1T slice + 0.4MB asT/adT slice (fits 4MB).
// Wave = one (dst, head). Lanes: e8 = lane>>3 (edge slot), c4 = lane&7 (4 channels, uint2).
// 16 edges in flight per iter; no shuffles in steady loop; one xor-tree reduce per dst.
__global__ __launch_bounds__(256) void agg1_csr_k(
        const int* __restrict__ row_start, const int* __restrict__ csr_src,
        const unsigned short* __restrict__ z1T, const float* __restrict__ asT,
        const float* __restrict__ adT, const float* __restrict__ b,
        unsigned short* __restrict__ h1) {
    int h = blockIdx.x & 7;
    int dblk = blockIdx.x >> 3;
    int wv = threadIdx.x >> 6, lane = threadIdx.x & 63;
    int d = dblk * 4 + wv;
    int e8 = lane >> 3, c4 = lane & 7;
    const float* ash = asT + (size_t)h * NNODES;
    const unsigned short* zh = z1T + (size_t)h * NNODES * 32;
    float adh = adT[(size_t)h * NNODES + d];
    int beg = row_start[d], end = row_start[d + 1];
    float sum = 0.f, a0 = 0.f, a1 = 0.f, a2 = 0.f, a3 = 0.f;
    for (int i = beg; i < end; i += 16) {
        int i0 = i + e8, i1 = i + 8 + e8;
        int s0 = csr_src[i0 < end ? i0 : end - 1];
        int s1 = csr_src[i1 < end ? i1 : end - 1];
        float w0 = __expf(lrelu(ash[s0] + adh));
        float w1 = __expf(lrelu(ash[s1] + adh));
        w0 = (i0 < end) ? w0 : 0.f;
        w1 = (i1 < end) ? w1 : 0.f;
        uint2 q0 = *(const uint2*)(zh + (size_t)s0 * 32 + c4 * 4);
        uint2 q1 = *(const uint2*)(zh + (size_t)s1 * 32 + c4 * 4);
        sum += w0 + w1;
        a0 += w0 * bflo(q0.x) + w1 * bflo(q1.x);
        a1 += w0 * bfhi(q0.x) + w1 * bfhi(q1.x);
        a2 += w0 * bflo(q0.y) + w1 * bflo(q1.y);
        a3 += w0 * bfhi(q0.y) + w1 * bfhi(q1.y);
    }
    // reduce over edge slots (lane bits 3..5)
#pragma unroll
    for (int off = 8; off < 64; off <<= 1) {
        sum += __shfl_xor(sum, off, 64);
        a0 += __shfl_xor(a0, off, 64);
        a1 += __shfl_xor(a1, off, 64);
        a2 += __shfl_xor(a2, off, 64);
        a3 += __shfl_xor(a3, off, 64);
    }
    if (e8 == 0) {
        int c0 = h * 32 + c4 * 4;
        float inv = 1.f / sum;
        float o0 = a0 * inv + b[c0 + 0];
        float o1 = a1 * inv + b[c0 + 1];
        float o2 = a2 * inv + b[c0 + 2];
        float o3 = a3 * inv + b[c0 + 3];
        o0 = o0 > 0.f ? o0 : expm1f(o0);
        o1 = o1 > 0.f ? o1 : expm1f(o1);
        o2 = o2 > 0.f ? o2 : expm1f(o2);
        o3 = o3 > 0.f ? o3 : expm1f(o3);
        uint2 pk;
        pk.x = (unsigned)f2bf(o0) | ((unsigned)f2bf(o1) << 16);
        pk.y = (unsigned)f2bf(o2) | ((unsigned)f2bf(o3) << 16);
        *(uint2*)(h1 + (size_t)d * 256 + c0) = pk;
    }
}

// ---------- fused layer-2 aggregation + bias: 16 lanes/dst, 2 bf16 ch/lane ----------
__global__ void agg2_csr_k(const int* __restrict__ row_start, const int* __restrict__ csr_src,
                           const unsigned short* __restrict__ z2b, const float* __restrict__ as_,
                           const float* __restrict__ ad_, const float* __restrict__ b,
                           float* __restrict__ out) {
    int g = blockIdx.x * 16 + (threadIdx.x >> 4);   // 16 dsts per 256-thr block
    int l = threadIdx.x & 15;
    int lane = threadIdx.x & 63;
    int c0 = l * 2;
    int beg = row_start[g], end = row_start[g + 1];
    float adn = ad_[g];
    int e8 = l & 7;
    int gb = lane & 48;                             // 16-lane group base within wave
    float sum = 0.f, a0 = 0.f, a1 = 0.f;
    int i = beg;
    for (; i + 8 <= end; i += 8) {
        int sv = csr_src[i + e8];
        float myw = __expf(lrelu(as_[sv] + adn));
        int se[8];
        float we[8];
#pragma unroll
        for (int e = 0; e < 8; ++e) {
            se[e] = __shfl(sv, gb | e, 64);
            we[e] = __shfl(myw, gb | (8 | e), 64);
        }
        unsigned q[8];
#pragma unroll
        for (int e = 0; e < 8; ++e)
            q[e] = *(const unsigned*)(z2b + (size_t)se[e] * 32 + c0);
#pragma unroll
        for (int e = 0; e < 8; ++e) {
            float wgt = we[e];
            sum += wgt;
            a0 += wgt * bflo(q[e]);
            a1 += wgt * bfhi(q[e]);
        }
    }
    for (; i < end; ++i) {
        int s = csr_src[i];
        float wgt = __expf(lrelu(as_[s] + adn));
        unsigned q = *(const unsigned*)(z2b + (size_t)s * 32 + c0);
        sum += wgt;
        a0 += wgt * bflo(q);
        a1 += wgt * bfhi(q);
    }
    float inv = 1.f / sum;
    float2 o;
    o.x = a0 * inv + b[c0];
    o.y = a1 * inv + b[c0 + 1];
    *(float2*)(out + (size_t)g * 32 + c0) = o;
}

extern "C" void kernel_launch(void* const* d_in, const int* in_sizes, int n_in,
                              void* d_out, int out_size, void* d_ws, size_t ws_size,
                              hipStream_t stream) {
    const float* x   = (const float*)d_in[0];
    const int*   ei  = (const int*)d_in[1];
    const float* W1  = (const float*)d_in[2];
    const float* av1 = (const float*)d_in[3];
    const float* bv1 = (const float*)d_in[4];
    const float* b1  = (const float*)d_in[5];
    const float* W2  = (const float*)d_in[6];
    const float* av2 = (const float*)d_in[7];
    const float* bv2 = (const float*)d_in[8];
    const float* b2  = (const float*)d_in[9];
    float* out = (float*)d_out;

    // workspace layout (4-byte units)
    unsigned short* z1T = (unsigned short*)d_ws;           // 12.8M bf16 = 6.4M u32 (head-major)
    unsigned short* h1 = (unsigned short*)((float*)d_ws + 6400000);  // 12.8M bf16
    float* as1 = (float*)d_ws + 12800000;                  // 400,000 (transposed [8][50000])
    float* ad1 = as1 + 400000;                             // 400,000 (transposed [8][50000])
    unsigned short* z2b = (unsigned short*)(ad1 + 400000); // 1.6M bf16 = 800,000 u32
    float* as2 = ad1 + 400000 + 800000;                    // 50,000
    float* ad2 = as2 + 50000;                              // 50,000
    short8* W1frag = (short8*)(ad2 + 50000);               // 8192 * 16 B
    short8* W2frag = W1frag + 8192;                        // 1024 * 16 B
    int* deg       = (int*)(ad2 + 50000) + 36864;          // 50,000
    int* row_start = deg + 50000;                          // 50,001
    int* csr_src   = row_start + 50001;                    // 850,000
    int* row_local = csr_src + 850000;                     // 50,000
    int* bsum      = row_local + 50000;                    // 256
    // pos aliases z2b: written by wprep_hist, consumed by gemm1_scatter, dead before gemm2
    unsigned short* pos = (unsigned short*)z2b;            // 850,000 u16

    hipMemsetAsync(deg, 0, (size_t)50000 * 4, stream);

    // ---- weight prep + histogram (+ per-edge rank) + scan ----
    wprep_hist_k<<<36 + SCAT_BLKS, 256, 0, stream>>>(W1, W2, W1frag, W2frag, ei, deg, pos);
    scan_part_k<<<NSCAN_BLK, 256, 0, stream>>>(deg, row_local, bsum);
    scan_fix_k<<<NSCAN_BLK, 256, 0, stream>>>(row_local, bsum, row_start);

    // ---- layer 1 (gemm1 fused with atomic-free CSR scatter) ----
    gemm1_scatter_k<<<GEMM1_BLKS + SCAT_BLKS, 256, 0, stream>>>(
        x, W1frag, av1, bv1, z1T, as1, ad1, ei, row_start, pos, csr_src);
    agg1_csr_k<<<AGG1_BLKS, 256, 0, stream>>>(row_start, csr_src, z1T, as1, ad1, b1, h1);

    // ---- layer 2 ----
    gemm2_mfma_k<<<(NNODES + 63) / 64, 256, 0, stream>>>(h1, W2frag, av2, bv2, z2b, as2, ad2);
    agg2_csr_k<<<NNODES / 16, 256, 0, stream>>>(row_start, csr_src, z2b, as2, ad2, b2, out);
}

// Round 2
// 335.021 us; speedup vs baseline: 1.0815x; 1.0815x over previous
//
#include <hip/hip_runtime.h>

#define NNODES 50000
#define NFEAT 256
#define NHID 32
#define NHEADS 8
#define NCLASSES 32
#define NEDGES 800000
#define ETOT (NEDGES + NNODES)   // 850000 with self loops
#define NSCAN_BLK 196            // ceil(50000/256)
#define GEMM1_BLKS 782           // ceil(50000/64)
#define SCAT_BLKS 3321           // ceil(850000/256)
#define XCONV_BLKS 6250          // 50000*256/8 elems / 256 thr
#define AGG1_BLKS 25000          // 3125 dst-blocks (16 dst each) * 8 head slices

typedef __attribute__((ext_vector_type(8))) short short8;
typedef __attribute__((ext_vector_type(4))) float f32x4;

__device__ __forceinline__ void get_edge(const int* __restrict__ ei, int e,
                                         int& s, int& d) {
    if (e < NEDGES) { s = ei[e]; d = ei[NEDGES + e]; }
    else            { s = e - NEDGES; d = s; }
}
__device__ __forceinline__ float lrelu(float x) { return x > 0.f ? x : 0.2f * x; }
__device__ __forceinline__ unsigned short f2bf(float f) {   // RNE
    unsigned u = __float_as_uint(f);
    unsigned r = u + 0x7fffu + ((u >> 16) & 1u);
    return (unsigned short)(r >> 16);
}
__device__ __forceinline__ float bflo(unsigned u) { return __uint_as_float(u << 16); }
__device__ __forceinline__ float bfhi(unsigned u) { return __uint_as_float(u & 0xffff0000u); }

// ---------- fused: weight prep (0..35) + x->bf16 (36..36+6249) + hist+rank (rest) ----------
// pos[e] = within-dst arrival rank, from the SAME atomicAdd that builds the histogram.
__global__ void wprep_hist_k(const float* __restrict__ W1, const float* __restrict__ W2,
                             short8* __restrict__ W1frag, short8* __restrict__ W2frag,
                             const float* __restrict__ x, short8* __restrict__ xbf,
                             const int* __restrict__ ei, int* __restrict__ deg,
                             unsigned short* __restrict__ pos) {
    if (blockIdx.x < 36) {
        int idx = blockIdx.x * 256 + threadIdx.x;
        if (idx < 8192) {
            int kc = idx >> 10, r = idx & 1023;
            int nt = r >> 6, lane = r & 63;
            int l16 = lane & 15, quad = lane >> 4;
            int n = nt * 16 + l16, k0 = kc * 32 + quad * 8;
            short8 v;
#pragma unroll
            for (int j = 0; j < 8; ++j) v[j] = (short)f2bf(W1[(k0 + j) * 256 + n]);
            W1frag[idx] = v;
        } else if (idx < 8192 + 1024) {
            int g = idx - 8192;
            int kc = g >> 7, r = g & 127;
            int nt = r >> 6, lane = r & 63;
            int l16 = lane & 15, quad = lane >> 4;
            int n = nt * 16 + l16, k0 = kc * 32 + quad * 8;
            short8 v;
#pragma unroll
            for (int j = 0; j < 8; ++j) v[j] = (short)f2bf(W2[(k0 + j) * 32 + n]);
            W2frag[g] = v;
        }
    } else if (blockIdx.x < 36 + XCONV_BLKS) {
        int idx = (blockIdx.x - 36) * 256 + threadIdx.x;   // < 1,600,000
        const float4* xp = (const float4*)(x + (size_t)idx * 8);
        float4 v0 = xp[0], v1 = xp[1];
        short8 o;
        o[0] = (short)f2bf(v0.x); o[1] = (short)f2bf(v0.y);
        o[2] = (short)f2bf(v0.z); o[3] = (short)f2bf(v0.w);
        o[4] = (short)f2bf(v1.x); o[5] = (short)f2bf(v1.y);
        o[6] = (short)f2bf(v1.z); o[7] = (short)f2bf(v1.w);
        xbf[idx] = o;
    } else {
        int e = (blockIdx.x - 36 - XCONV_BLKS) * 256 + threadIdx.x;
        if (e >= ETOT) return;
        int d = (e < NEDGES) ? ei[NEDGES + e] : (e - NEDGES);
        pos[e] = (unsigned short)atomicAdd(&deg[d], 1);
    }
}

// ---------- parallel scan, phase 1: per-block exclusive scan + block sums ----------
__global__ void scan_part_k(const int* __restrict__ deg, int* __restrict__ row_local,
                            int* __restrict__ bsum) {
    __shared__ int ws[4];
    int t = threadIdx.x, lane = t & 63, wid = t >> 6;
    int idx = blockIdx.x * 256 + t;
    int v = (idx < NNODES) ? deg[idx] : 0;
    int inc = v;
#pragma unroll
    for (int off = 1; off < 64; off <<= 1) {
        int u = __shfl_up(inc, off, 64);
        if (lane >= off) inc += u;
    }
    if (lane == 63) ws[wid] = inc;
    __syncthreads();
    int woff = 0;
#pragma unroll
    for (int j = 0; j < 4; ++j) woff += (j < wid) ? ws[j] : 0;
    if (idx < NNODES) row_local[idx] = woff + inc - v;
    if (t == 255) bsum[blockIdx.x] = woff + inc;
}

// ---------- scan phase 2+3 merged ----------
__global__ void scan_fix_k(const int* __restrict__ row_local, const int* __restrict__ bsum,
                           int* __restrict__ row_start) {
    __shared__ int ws[4];
    __shared__ int sboff;
    int t = threadIdx.x, lane = t & 63, wid = t >> 6;
    int v = (t < NSCAN_BLK) ? bsum[t] : 0;
    int inc = v;
#pragma unroll
    for (int off = 1; off < 64; off <<= 1) {
        int u = __shfl_up(inc, off, 64);
        if (lane >= off) inc += u;
    }
    if (lane == 63) ws[wid] = inc;
    __syncthreads();
    int woff = 0;
#pragma unroll
    for (int j = 0; j < 4; ++j) woff += (j < wid) ? ws[j] : 0;
    if (t == blockIdx.x) sboff = woff + inc - v;
    __syncthreads();
    int idx = blockIdx.x * 256 + t;
    if (idx < NNODES) row_start[idx] = row_local[idx] + sboff;
    if (idx == 0) row_start[NNODES] = ETOT;
}

// ---------- fused GEMM1 (MFMA bf16, barrier-free, x preloaded in regs) + attn1 + scatter ----------
// z1 head-major: z1T[h][node][32] bf16. as/ad transposed: asT[h][node], adT[h][node].
// No LDS: W fragments are identical broadcasts for all waves -> L1/L2-hot.
__global__ __launch_bounds__(256) void gemm1_scatter_k(
        const short8* __restrict__ xbf, const short8* __restrict__ Wfrag,
        const float* __restrict__ av, const float* __restrict__ bv,
        unsigned short* __restrict__ z1T, float* __restrict__ asT, float* __restrict__ adT,
        const int* __restrict__ ei, const int* __restrict__ row_start,
        const unsigned short* __restrict__ pos, int* __restrict__ csr_src) {
    if (blockIdx.x >= GEMM1_BLKS) {
        int e = (blockIdx.x - GEMM1_BLKS) * 256 + threadIdx.x;
        if (e >= ETOT) return;
        int s, d;
        get_edge(ei, e, s, d);
        csr_src[row_start[d] + (int)pos[e]] = s;    // no atomic: rank precomputed
        return;
    }
    int t = threadIdx.x;
    int w = t >> 6, lane = t & 63;
    int quad = lane >> 4, l16 = lane & 15;
    int mA = blockIdx.x * 64 + w * 16 + l16;
    int mAl = min(mA, NNODES - 1);

    // preload this lane's full bf16 x-row slice: 8 x short8 = 32 VGPR, one-time latency
    const short8* xr = xbf + (size_t)mAl * 32;
    short8 xreg[8];
#pragma unroll
    for (int kc = 0; kc < 8; ++kc) xreg[kc] = xr[kc * 4 + quad];

    f32x4 acc[16];
#pragma unroll
    for (int nt = 0; nt < 16; ++nt) acc[nt] = (f32x4){0.f, 0.f, 0.f, 0.f};

#pragma unroll
    for (int kc = 0; kc < 8; ++kc) {
        short8 af = xreg[kc];
#pragma unroll
        for (int nt = 0; nt < 16; ++nt) {
            short8 bf8 = Wfrag[kc * 1024 + nt * 64 + lane];
            acc[nt] = __builtin_amdgcn_mfma_f32_16x16x32_bf16(af, bf8, acc[nt], 0, 0, 0);
        }
    }
    int mrow0 = blockIdx.x * 64 + w * 16 + quad * 4;
#pragma unroll
    for (int nt = 0; nt < 16; ++nt) {
        int hh = nt >> 1, cc = (nt & 1) * 16 + l16;
#pragma unroll
        for (int r = 0; r < 4; ++r) {
            int mr = mrow0 + r;
            if (mr < NNODES)
                z1T[((size_t)hh * NNODES + mr) * 32 + cc] = f2bf(acc[nt][r]);
        }
    }
#pragma unroll
    for (int h = 0; h < 8; ++h) {
        float av0 = av[(2 * h) * 16 + l16], av1v = av[(2 * h + 1) * 16 + l16];
        float bv0 = bv[(2 * h) * 16 + l16], bv1v = bv[(2 * h + 1) * 16 + l16];
#pragma unroll
        for (int r = 0; r < 4; ++r) {
            float pa = acc[2 * h][r] * av0 + acc[2 * h + 1][r] * av1v;
            float pb = acc[2 * h][r] * bv0 + acc[2 * h + 1][r] * bv1v;
#pragma unroll
            for (int off = 1; off < 16; off <<= 1) {
                pa += __shfl_xor(pa, off, 64);
                pb += __shfl_xor(pb, off, 64);
            }
            int mr = mrow0 + r;
            if (l16 == 0 && mr < NNODES) {
                asT[(size_t)h * NNODES + mr] = pa;
                adT[(size_t)h * NNODES + mr] = pb;
            }
        }
    }
}

// ---------- GEMM2 (MFMA bf16) + fused attn2 epilogue; z2 stored bf16 ----------
__global__ __launch_bounds__(256) void gemm2_mfma_k(
        const unsigned short* __restrict__ h1, const short8* __restrict__ Wfrag,
        const float* __restrict__ av, const float* __restrict__ bv,
        unsigned short* __restrict__ z2b, float* __restrict__ as_, float* __restrict__ ad_) {
    int w = threadIdx.x >> 6, lane = threadIdx.x & 63;
    int quad = lane >> 4, l16 = lane & 15;
    int mA = blockIdx.x * 64 + w * 16 + l16;
    int mAl = min(mA, NNODES - 1);

    f32x4 acc[2];
    acc[0] = (f32x4){0.f, 0.f, 0.f, 0.f};
    acc[1] = (f32x4){0.f, 0.f, 0.f, 0.f};
    for (int kc = 0; kc < 8; ++kc) {
        int k0 = kc * 32 + quad * 8;
        short8 af = *(const short8*)(h1 + (size_t)mAl * 256 + k0);
#pragma unroll
        for (int nt = 0; nt < 2; ++nt) {
            short8 bf8 = Wfrag[kc * 128 + nt * 64 + lane];
            acc[nt] = __builtin_amdgcn_mfma_f32_16x16x32_bf16(af, bf8, acc[nt], 0, 0, 0);
        }
    }
    int mrow0 = blockIdx.x * 64 + w * 16 + quad * 4;
    float av0 = av[l16], av1v = av[16 + l16];
    float bv0 = bv[l16], bv1v = bv[16 + l16];
#pragma unroll
    for (int r = 0; r < 4; ++r) {
        int mr = mrow0 + r;
        float pa = acc[0][r] * av0 + acc[1][r] * av1v;
        float pb = acc[0][r] * bv0 + acc[1][r] * bv1v;
#pragma unroll
        for (int off = 1; off < 16; off <<= 1) {
            pa += __shfl_xor(pa, off, 64);
            pb += __shfl_xor(pb, off, 64);
        }
        if (mr < NNODES) {
            z2b[(size_t)mr * 32 + l16] = f2bf(acc[0][r]);
            z2b[(size_t)mr * 32 + 16 + l16] = f2bf(acc[1][r]);
            if (l16 == 0) { as_[mr] = pa; ad_[mr] = pb; }
        }
    }
}

// ---------- layer-1 aggregation: head-sliced + XCD-affine, agg2-style loop ----------
// blockIdx.x & 7 = head -> round-robin block->XCD pins each head slice to one XCD L2
// (z1T slice 3.2MB + asT/adT slices 0.4MB fit the 4MB XCD L2 -> gather is L2-resident).
// Loop shape = proven agg2 pattern: 16 lanes/dst, 2 bf16 ch/lane, 8-edge strips,
// shuffle-dedup (all 64 lanes compute distinct useful weights; no clamping, no waste).
__global__ __launch_bounds__(256) void agg1_csr_k(
        const int* __restrict__ row_start, const int* __restrict__ csr_src,
        const unsigned short* __restrict__ z1T, const float* __restrict__ asT,
        const float* __restrict__ adT, const float* __restrict__ b,
        unsigned short* __restrict__ h1) {
    int h = blockIdx.x & 7;
    int dblk = blockIdx.x >> 3;
    int g = dblk * 16 + (threadIdx.x >> 4);         // dst node
    int l = threadIdx.x & 15;
    int lane = threadIdx.x & 63;
    int c0 = l * 2;                                 // 2 bf16 channels per lane
    const float* ash = asT + (size_t)h * NNODES;
    const unsigned short* zh = z1T + (size_t)h * NNODES * 32;
    int beg = row_start[g], end = row_start[g + 1];
    float adn = adT[(size_t)h * NNODES + g];
    int e8 = l & 7;
    int gb = lane & 48;                             // 16-lane group base within wave
    float sum = 0.f, a0 = 0.f, a1 = 0.f;
    int i = beg;
    for (; i + 8 <= end; i += 8) {
        int sv = csr_src[i + e8];
        float myw = __expf(lrelu(ash[sv] + adn));
        int se[8];
        float we[8];
#pragma unroll
        for (int e = 0; e < 8; ++e) {
            se[e] = __shfl(sv, gb | e, 64);
            we[e] = __shfl(myw, gb | (8 | e), 64);  // upper half computed same-edge weights
        }
        unsigned q[8];
#pragma unroll
        for (int e = 0; e < 8; ++e)
            q[e] = *(const unsigned*)(zh + (size_t)se[e] * 32 + c0);
#pragma unroll
        for (int e = 0; e < 8; ++e) {
            float wgt = we[e];
            sum += wgt;
            a0 += wgt * bflo(q[e]);
            a1 += wgt * bfhi(q[e]);
        }
    }
    for (; i < end; ++i) {
        int s = csr_src[i];
        float wgt = __expf(lrelu(ash[s] + adn));
        unsigned q = *(const unsigned*)(zh + (size_t)s * 32 + c0);
        sum += wgt;
        a0 += wgt * bflo(q);
        a1 += wgt * bfhi(q);
    }
    float inv = 1.f / sum;
    int cg = h * 32 + c0;
    float o0 = a0 * inv + b[cg];
    float o1 = a1 * inv + b[cg + 1];
    o0 = o0 > 0.f ? o0 : expm1f(o0);
    o1 = o1 > 0.f ? o1 : expm1f(o1);
    unsigned pk = (unsigned)f2bf(o0) | ((unsigned)f2bf(o1) << 16);
    *(unsigned*)(h1 + (size_t)g * 256 + cg) = pk;
}

// ---------- fused layer-2 aggregation + bias: 16 lanes/dst, 2 bf16 ch/lane ----------
__global__ void agg2_csr_k(const int* __restrict__ row_start, const int* __restrict__ csr_src,
                           const unsigned short* __restrict__ z2b, const float* __restrict__ as_,
                           const float* __restrict__ ad_, const float* __restrict__ b,
                           float* __restrict__ out) {
    int g = blockIdx.x * 16 + (threadIdx.x >> 4);   // 16 dsts per 256-thr block
    int l = threadIdx.x & 15;
    int lane = threadIdx.x & 63;
    int c0 = l * 2;
    int beg = row_start[g], end = row_start[g + 1];
    float adn = ad_[g];
    int e8 = l & 7;
    int gb = lane & 48;                             // 16-lane group base within wave
    float sum = 0.f, a0 = 0.f, a1 = 0.f;
    int i = beg;
    for (; i + 8 <= end; i += 8) {
        int sv = csr_src[i + e8];
        float myw = __expf(lrelu(as_[sv] + adn));
        int se[8];
        float we[8];
#pragma unroll
        for (int e = 0; e < 8; ++e) {
            se[e] = __shfl(sv, gb | e, 64);
            we[e] = __shfl(myw, gb | (8 | e), 64);
        }
        unsigned q[8];
#pragma unroll
        for (int e = 0; e < 8; ++e)
            q[e] = *(const unsigned*)(z2b + (size_t)se[e] * 32 + c0);
#pragma unroll
        for (int e = 0; e < 8; ++e) {
            float wgt = we[e];
            sum += wgt;
            a0 += wgt * bflo(q[e]);
            a1 += wgt * bfhi(q[e]);
        }
    }
    for (; i < end; ++i) {
        int s = csr_src[i];
        float wgt = __expf(lrelu(as_[s] + adn));
        unsigned q = *(const unsigned*)(z2b + (size_t)s * 32 + c0);
        sum += wgt;
        a0 += wgt * bflo(q);
        a1 += wgt * bfhi(q);
    }
    float inv = 1.f / sum;
    float2 o;
    o.x = a0 * inv + b[c0];
    o.y = a1 * inv + b[c0 + 1];
    *(float2*)(out + (size_t)g * 32 + c0) = o;
}

extern "C" void kernel_launch(void* const* d_in, const int* in_sizes, int n_in,
                              void* d_out, int out_size, void* d_ws, size_t ws_size,
                              hipStream_t stream) {
    const float* x   = (const float*)d_in[0];
    const int*   ei  = (const int*)d_in[1];
    const float* W1  = (const float*)d_in[2];
    const float* av1 = (const float*)d_in[3];
    const float* bv1 = (const float*)d_in[4];
    const float* b1  = (const float*)d_in[5];
    const float* W2  = (const float*)d_in[6];
    const float* av2 = (const float*)d_in[7];
    const float* bv2 = (const float*)d_in[8];
    const float* b2  = (const float*)d_in[9];
    float* out = (float*)d_out;

    // workspace layout (4-byte units)
    unsigned short* z1T = (unsigned short*)d_ws;           // 12.8M bf16 (head-major)
    unsigned short* h1 = (unsigned short*)((float*)d_ws + 6400000);  // 12.8M bf16
    float* as1 = (float*)d_ws + 12800000;                  // 400,000 (transposed [8][50000])
    float* ad1 = as1 + 400000;                             // 400,000 (transposed [8][50000])
    unsigned short* z2b = (unsigned short*)(ad1 + 400000); // 1.6M bf16
    float* as2 = ad1 + 400000 + 800000;                    // 50,000
    float* ad2 = as2 + 50000;                              // 50,000
    short8* W1frag = (short8*)(ad2 + 50000);               // 8192 * 16 B
    short8* W2frag = W1frag + 8192;                        // 1024 * 16 B
    int* deg       = (int*)(ad2 + 50000) + 36864;          // 50,000
    int* row_start = deg + 50000;                          // 50,001
    int* csr_src   = row_start + 50001;                    // 850,000
    int* row_local = csr_src + 850000;                     // 50,000
    int* bsum      = row_local + 50000;                    // 256
    // pos aliases z2b: written by wprep_hist, consumed by gemm1_scatter, dead before gemm2
    unsigned short* pos = (unsigned short*)z2b;            // 850,000 u16
    // xbf aliases h1: written by wprep_hist, consumed by gemm1_scatter, dead before agg1
    short8* xbf = (short8*)h1;                             // 1,600,000 short8 = 25.6 MB

    hipMemsetAsync(deg, 0, (size_t)50000 * 4, stream);

    // ---- weight prep + x->bf16 + histogram (+ per-edge rank) + scan ----
    wprep_hist_k<<<36 + XCONV_BLKS + SCAT_BLKS, 256, 0, stream>>>(
        W1, W2, W1frag, W2frag, x, xbf, ei, deg, pos);
    scan_part_k<<<NSCAN_BLK, 256, 0, stream>>>(deg, row_local, bsum);
    scan_fix_k<<<NSCAN_BLK, 256, 0, stream>>>(row_local, bsum, row_start);

    // ---- layer 1 (gemm1 fused with atomic-free CSR scatter) ----
    gemm1_scatter_k<<<GEMM1_BLKS + SCAT_BLKS, 256, 0, stream>>>(
        xbf, W1frag, av1, bv1, z1T, as1, ad1, ei, row_start, pos, csr_src);
    agg1_csr_k<<<AGG1_BLKS, 256, 0, stream>>>(row_start, csr_src, z1T, as1, ad1, b1, h1);

    // ---- layer 2 ----
    gemm2_mfma_k<<<(NNODES + 63) / 64, 256, 0, stream>>>(h1, W2frag, av2, bv2, z2b, as2, ad2);
    agg2_csr_k<<<NNODES / 16, 256, 0, stream>>>(row_start, csr_src, z2b, as2, ad2, b2, out);
}

// Round 4
// 307.804 us; speedup vs baseline: 1.1772x; 1.0884x over previous
//
#include <hip/hip_runtime.h>

#define NNODES 50000
#define NFEAT 256
#define NHID 32
#define NHEADS 8
#define NCLASSES 32
#define NEDGES 800000
#define ETOT (NEDGES + NNODES)   // 850000 with self loops
#define NSCAN_BLK 196            // ceil(50000/256)
#define GEMM1_BLKS 782           // ceil(50000/64)
#define SCAT_BLKS 3321           // ceil(850000/256)
#define XCONV_BLKS 6250          // 50000*256/8 elems / 256 thr
#define NDBLK 1563               // ceil(50000/32) dst-blocks of 32 dsts
#define AGG1_BLKS (NDBLK * 8)    // * 8 head slices (h = blockIdx & 7 -> XCD affine)

typedef __attribute__((ext_vector_type(8))) short short8;
typedef __attribute__((ext_vector_type(4))) float f32x4;

__device__ __forceinline__ void get_edge(const int* __restrict__ ei, int e,
                                         int& s, int& d) {
    if (e < NEDGES) { s = ei[e]; d = ei[NEDGES + e]; }
    else            { s = e - NEDGES; d = s; }
}
__device__ __forceinline__ float lrelu(float x) { return x > 0.f ? x : 0.2f * x; }
__device__ __forceinline__ unsigned short f2bf(float f) {   // RNE
    unsigned u = __float_as_uint(f);
    unsigned r = u + 0x7fffu + ((u >> 16) & 1u);
    return (unsigned short)(r >> 16);
}
__device__ __forceinline__ float bflo(unsigned u) { return __uint_as_float(u << 16); }
__device__ __forceinline__ float bfhi(unsigned u) { return __uint_as_float(u & 0xffff0000u); }

// ---------- fused: weight prep (0..35) + x->bf16 (36..36+6249) + hist+rank (rest) ----------
__global__ void wprep_hist_k(const float* __restrict__ W1, const float* __restrict__ W2,
                             short8* __restrict__ W1frag, short8* __restrict__ W2frag,
                             const float* __restrict__ x, short8* __restrict__ xbf,
                             const int* __restrict__ ei, int* __restrict__ deg,
                             unsigned short* __restrict__ pos) {
    if (blockIdx.x < 36) {
        int idx = blockIdx.x * 256 + threadIdx.x;
        if (idx < 8192) {
            int kc = idx >> 10, r = idx & 1023;
            int nt = r >> 6, lane = r & 63;
            int l16 = lane & 15, quad = lane >> 4;
            int n = nt * 16 + l16, k0 = kc * 32 + quad * 8;
            short8 v;
#pragma unroll
            for (int j = 0; j < 8; ++j) v[j] = (short)f2bf(W1[(k0 + j) * 256 + n]);
            W1frag[idx] = v;
        } else if (idx < 8192 + 1024) {
            int g = idx - 8192;
            int kc = g >> 7, r = g & 127;
            int nt = r >> 6, lane = r & 63;
            int l16 = lane & 15, quad = lane >> 4;
            int n = nt * 16 + l16, k0 = kc * 32 + quad * 8;
            short8 v;
#pragma unroll
            for (int j = 0; j < 8; ++j) v[j] = (short)f2bf(W2[(k0 + j) * 32 + n]);
            W2frag[g] = v;
        }
    } else if (blockIdx.x < 36 + XCONV_BLKS) {
        int idx = (blockIdx.x - 36) * 256 + threadIdx.x;   // < 1,600,000
        const float4* xp = (const float4*)(x + (size_t)idx * 8);
        float4 v0 = xp[0], v1 = xp[1];
        short8 o;
        o[0] = (short)f2bf(v0.x); o[1] = (short)f2bf(v0.y);
        o[2] = (short)f2bf(v0.z); o[3] = (short)f2bf(v0.w);
        o[4] = (short)f2bf(v1.x); o[5] = (short)f2bf(v1.y);
        o[6] = (short)f2bf(v1.z); o[7] = (short)f2bf(v1.w);
        xbf[idx] = o;
    } else {
        int e = (blockIdx.x - 36 - XCONV_BLKS) * 256 + threadIdx.x;
        if (e >= ETOT) return;
        int d = (e < NEDGES) ? ei[NEDGES + e] : (e - NEDGES);
        pos[e] = (unsigned short)atomicAdd(&deg[d], 1);
    }
}

// ---------- parallel scan, phase 1 ----------
__global__ void scan_part_k(const int* __restrict__ deg, int* __restrict__ row_local,
                            int* __restrict__ bsum) {
    __shared__ int ws[4];
    int t = threadIdx.x, lane = t & 63, wid = t >> 6;
    int idx = blockIdx.x * 256 + t;
    int v = (idx < NNODES) ? deg[idx] : 0;
    int inc = v;
#pragma unroll
    for (int off = 1; off < 64; off <<= 1) {
        int u = __shfl_up(inc, off, 64);
        if (lane >= off) inc += u;
    }
    if (lane == 63) ws[wid] = inc;
    __syncthreads();
    int woff = 0;
#pragma unroll
    for (int j = 0; j < 4; ++j) woff += (j < wid) ? ws[j] : 0;
    if (idx < NNODES) row_local[idx] = woff + inc - v;
    if (t == 255) bsum[blockIdx.x] = woff + inc;
}

// ---------- scan phase 2+3 merged ----------
__global__ void scan_fix_k(const int* __restrict__ row_local, const int* __restrict__ bsum,
                           int* __restrict__ row_start) {
    __shared__ int ws[4];
    __shared__ int sboff;
    int t = threadIdx.x, lane = t & 63, wid = t >> 6;
    int v = (t < NSCAN_BLK) ? bsum[t] : 0;
    int inc = v;
#pragma unroll
    for (int off = 1; off < 64; off <<= 1) {
        int u = __shfl_up(inc, off, 64);
        if (lane >= off) inc += u;
    }
    if (lane == 63) ws[wid] = inc;
    __syncthreads();
    int woff = 0;
#pragma unroll
    for (int j = 0; j < 4; ++j) woff += (j < wid) ? ws[j] : 0;
    if (t == blockIdx.x) sboff = woff + inc - v;
    __syncthreads();
    int idx = blockIdx.x * 256 + t;
    if (idx < NNODES) row_start[idx] = row_local[idx] + sboff;
    if (idx == 0) row_start[NNODES] = ETOT;
}

// ---------- fused GEMM1 (MFMA bf16, barrier-free, x preloaded in regs) + attn1 + scatter ----------
__global__ __launch_bounds__(256) void gemm1_scatter_k(
        const short8* __restrict__ xbf, const short8* __restrict__ Wfrag,
        const float* __restrict__ av, const float* __restrict__ bv,
        unsigned short* __restrict__ z1T, float* __restrict__ asT, float* __restrict__ adT,
        const int* __restrict__ ei, const int* __restrict__ row_start,
        const unsigned short* __restrict__ pos, int* __restrict__ csr_src) {
    if (blockIdx.x >= GEMM1_BLKS) {
        int e = (blockIdx.x - GEMM1_BLKS) * 256 + threadIdx.x;
        if (e >= ETOT) return;
        int s, d;
        get_edge(ei, e, s, d);
        csr_src[row_start[d] + (int)pos[e]] = s;    // no atomic: rank precomputed
        return;
    }
    int t = threadIdx.x;
    int w = t >> 6, lane = t & 63;
    int quad = lane >> 4, l16 = lane & 15;
    int mA = blockIdx.x * 64 + w * 16 + l16;
    int mAl = min(mA, NNODES - 1);

    const short8* xr = xbf + (size_t)mAl * 32;
    short8 xreg[8];
#pragma unroll
    for (int kc = 0; kc < 8; ++kc) xreg[kc] = xr[kc * 4 + quad];

    f32x4 acc[16];
#pragma unroll
    for (int nt = 0; nt < 16; ++nt) acc[nt] = (f32x4){0.f, 0.f, 0.f, 0.f};

#pragma unroll
    for (int kc = 0; kc < 8; ++kc) {
        short8 af = xreg[kc];
#pragma unroll
        for (int nt = 0; nt < 16; ++nt) {
            short8 bf8 = Wfrag[kc * 1024 + nt * 64 + lane];
            acc[nt] = __builtin_amdgcn_mfma_f32_16x16x32_bf16(af, bf8, acc[nt], 0, 0, 0);
        }
    }
    int mrow0 = blockIdx.x * 64 + w * 16 + quad * 4;
#pragma unroll
    for (int nt = 0; nt < 16; ++nt) {
        int hh = nt >> 1, cc = (nt & 1) * 16 + l16;
#pragma unroll
        for (int r = 0; r < 4; ++r) {
            int mr = mrow0 + r;
            if (mr < NNODES)
                z1T[((size_t)hh * NNODES + mr) * 32 + cc] = f2bf(acc[nt][r]);
        }
    }
#pragma unroll
    for (int h = 0; h < 8; ++h) {
        float av0 = av[(2 * h) * 16 + l16], av1v = av[(2 * h + 1) * 16 + l16];
        float bv0 = bv[(2 * h) * 16 + l16], bv1v = bv[(2 * h + 1) * 16 + l16];
#pragma unroll
        for (int r = 0; r < 4; ++r) {
            float pa = acc[2 * h][r] * av0 + acc[2 * h + 1][r] * av1v;
            float pb = acc[2 * h][r] * bv0 + acc[2 * h + 1][r] * bv1v;
#pragma unroll
            for (int off = 1; off < 16; off <<= 1) {
                pa += __shfl_xor(pa, off, 64);
                pb += __shfl_xor(pb, off, 64);
            }
            int mr = mrow0 + r;
            if (l16 == 0 && mr < NNODES) {
                asT[(size_t)h * NNODES + mr] = pa;
                adT[(size_t)h * NNODES + mr] = pb;
            }
        }
    }
}

// ---------- GEMM2 (MFMA bf16) + fused attn2 epilogue; z2 stored bf16 ----------
__global__ __launch_bounds__(256) void gemm2_mfma_k(
        const unsigned short* __restrict__ h1, const short8* __restrict__ Wfrag,
        const float* __restrict__ av, const float* __restrict__ bv,
        unsigned short* __restrict__ z2b, float* __restrict__ as_, float* __restrict__ ad_) {
    int w = threadIdx.x >> 6, lane = threadIdx.x & 63;
    int quad = lane >> 4, l16 = lane & 15;
    int mA = blockIdx.x * 64 + w * 16 + l16;
    int mAl = min(mA, NNODES - 1);

    f32x4 acc[2];
    acc[0] = (f32x4){0.f, 0.f, 0.f, 0.f};
    acc[1] = (f32x4){0.f, 0.f, 0.f, 0.f};
    for (int kc = 0; kc < 8; ++kc) {
        int k0 = kc * 32 + quad * 8;
        short8 af = *(const short8*)(h1 + (size_t)mAl * 256 + k0);
#pragma unroll
        for (int nt = 0; nt < 2; ++nt) {
            short8 bf8 = Wfrag[kc * 128 + nt * 64 + lane];
            acc[nt] = __builtin_amdgcn_mfma_f32_16x16x32_bf16(af, bf8, acc[nt], 0, 0, 0);
        }
    }
    int mrow0 = blockIdx.x * 64 + w * 16 + quad * 4;
    float av0 = av[l16], av1v = av[16 + l16];
    float bv0 = bv[l16], bv1v = bv[16 + l16];
#pragma unroll
    for (int r = 0; r < 4; ++r) {
        int mr = mrow0 + r;
        float pa = acc[0][r] * av0 + acc[1][r] * av1v;
        float pb = acc[0][r] * bv0 + acc[1][r] * bv1v;
#pragma unroll
        for (int off = 1; off < 16; off <<= 1) {
            pa += __shfl_xor(pa, off, 64);
            pb += __shfl_xor(pb, off, 64);
        }
        if (mr < NNODES) {
            z2b[(size_t)mr * 32 + l16] = f2bf(acc[0][r]);
            z2b[(size_t)mr * 32 + 16 + l16] = f2bf(acc[1][r]);
            if (l16 == 0) { as_[mr] = pa; ad_[mr] = pb; }
        }
    }
}

// ---------- layer-1 aggregation: head-sliced + XCD-affine, 8 lanes/dst, pipelined ----------
// h = blockIdx&7 pins each head slice (z1T 3.2MB + asT/adT 0.4MB) to one XCD L2.
// 8-lane group = 1 dst: c8 = lane&7 doubles as channel group (uint2 = 4ch = full 64B
// head row across the group) AND edge slot (8 edges/strip, shuffle-dedup weights).
// Masked strips (clamped idx, w=0) replace the tail loop. 2-deep pipeline: next
// strip's csr load + as-gather + exp overlap current strip's z-load batch.
__global__ __launch_bounds__(256) void agg1_csr_k(
        const int* __restrict__ row_start, const int* __restrict__ csr_src,
        const unsigned short* __restrict__ z1T, const float* __restrict__ asT,
        const float* __restrict__ adT, const float* __restrict__ b,
        unsigned short* __restrict__ h1) {
    int h = blockIdx.x & 7;
    int dblk = blockIdx.x >> 3;
    int lane = threadIdx.x & 63;
    int grp = threadIdx.x >> 3;          // 0..31 dst-groups per block
    int c8 = threadIdx.x & 7;            // channel-group AND edge-slot
    int gb = lane & 56;                  // 8-lane group base within wave
    int g = dblk * 32 + grp;
    int gl = min(g, NNODES - 1);
    const float* ash = asT + (size_t)h * NNODES;
    const unsigned short* zh = z1T + (size_t)h * NNODES * 32;
    int beg = row_start[gl], end = row_start[gl + 1];
    float adn = adT[(size_t)h * NNODES + gl];
    float sum = 0.f, a0 = 0.f, a1 = 0.f, a2 = 0.f, a3 = 0.f;

    // pipeline prologue: strip 0's index + weight
    int idx = beg + c8;
    int sv = csr_src[idx < end ? idx : end - 1];
    float wmy = __expf(lrelu(ash[sv] + adn));
    wmy = (idx < end) ? wmy : 0.f;

    for (int i = beg; i < end; i += 8) {
        // prefetch strip n+1 (clamped; overlaps current z-load batch)
        int idx2 = i + 8 + c8;
        int sv2 = csr_src[idx2 < end ? idx2 : end - 1];
        float wmy2 = __expf(lrelu(ash[sv2] + adn));
        wmy2 = (idx2 < end) ? wmy2 : 0.f;

        int se[8];
        float we[8];
#pragma unroll
        for (int e = 0; e < 8; ++e) {
            se[e] = __shfl(sv, gb | e, 64);
            we[e] = __shfl(wmy, gb | e, 64);
        }
#pragma unroll
        for (int e = 0; e < 8; ++e) {
            uint2 q = *(const uint2*)(zh + (size_t)se[e] * 32 + c8 * 4);
            float wg = we[e];
            sum += wg;
            a0 += wg * bflo(q.x);
            a1 += wg * bfhi(q.x);
            a2 += wg * bflo(q.y);
            a3 += wg * bfhi(q.y);
        }
        sv = sv2;
        wmy = wmy2;
    }
    if (g < NNODES) {
        int cg = h * 32 + c8 * 4;
        float inv = 1.f / sum;               // all 8 lanes hold the full sum
        float o0 = a0 * inv + b[cg + 0];
        float o1 = a1 * inv + b[cg + 1];
        float o2 = a2 * inv + b[cg + 2];
        float o3 = a3 * inv + b[cg + 3];
        o0 = o0 > 0.f ? o0 : expm1f(o0);
        o1 = o1 > 0.f ? o1 : expm1f(o1);
        o2 = o2 > 0.f ? o2 : expm1f(o2);
        o3 = o3 > 0.f ? o3 : expm1f(o3);
        uint2 pk;
        pk.x = (unsigned)f2bf(o0) | ((unsigned)f2bf(o1) << 16);
        pk.y = (unsigned)f2bf(o2) | ((unsigned)f2bf(o3) << 16);
        *(uint2*)(h1 + (size_t)g * 256 + cg) = pk;
    }
}

// ---------- layer-2 aggregation: same 8-lane/dst pipelined structure (z2b L2-resident) ----------
__global__ __launch_bounds__(256) void agg2_csr_k(
        const int* __restrict__ row_start, const int* __restrict__ csr_src,
        const unsigned short* __restrict__ z2b, const float* __restrict__ as_,
        const float* __restrict__ ad_, const float* __restrict__ b,
        float* __restrict__ out) {
    int lane = threadIdx.x & 63;
    int grp = threadIdx.x >> 3;
    int c8 = threadIdx.x & 7;
    int gb = lane & 56;
    int g = blockIdx.x * 32 + grp;
    int gl = min(g, NNODES - 1);
    int beg = row_start[gl], end = row_start[gl + 1];
    float adn = ad_[gl];
    float sum = 0.f, a0 = 0.f, a1 = 0.f, a2 = 0.f, a3 = 0.f;

    int idx = beg + c8;
    int sv = csr_src[idx < end ? idx : end - 1];
    float wmy = __expf(lrelu(as_[sv] + adn));
    wmy = (idx < end) ? wmy : 0.f;

    for (int i = beg; i < end; i += 8) {
        int idx2 = i + 8 + c8;
        int sv2 = csr_src[idx2 < end ? idx2 : end - 1];
        float wmy2 = __expf(lrelu(as_[sv2] + adn));
        wmy2 = (idx2 < end) ? wmy2 : 0.f;

        int se[8];
        float we[8];
#pragma unroll
        for (int e = 0; e < 8; ++e) {
            se[e] = __shfl(sv, gb | e, 64);
            we[e] = __shfl(wmy, gb | e, 64);
        }
#pragma unroll
        for (int e = 0; e < 8; ++e) {
            uint2 q = *(const uint2*)(z2b + (size_t)se[e] * 32 + c8 * 4);
            float wg = we[e];
            sum += wg;
            a0 += wg * bflo(q.x);
            a1 += wg * bfhi(q.x);
            a2 += wg * bflo(q.y);
            a3 += wg * bfhi(q.y);
        }
        sv = sv2;
        wmy = wmy2;
    }
    if (g < NNODES) {
        int cg = c8 * 4;
        float inv = 1.f / sum;
        float4 o;
        o.x = a0 * inv + b[cg + 0];
        o.y = a1 * inv + b[cg + 1];
        o.z = a2 * inv + b[cg + 2];
        o.w = a3 * inv + b[cg + 3];
        *(float4*)(out + (size_t)g * 32 + cg) = o;
    }
}

extern "C" void kernel_launch(void* const* d_in, const int* in_sizes, int n_in,
                              void* d_out, int out_size, void* d_ws, size_t ws_size,
                              hipStream_t stream) {
    const float* x   = (const float*)d_in[0];
    const int*   ei  = (const int*)d_in[1];
    const float* W1  = (const float*)d_in[2];
    const float* av1 = (const float*)d_in[3];
    const float* bv1 = (const float*)d_in[4];
    const float* b1  = (const float*)d_in[5];
    const float* W2  = (const float*)d_in[6];
    const float* av2 = (const float*)d_in[7];
    const float* bv2 = (const float*)d_in[8];
    const float* b2  = (const float*)d_in[9];
    float* out = (float*)d_out;

    // workspace layout (4-byte units)
    unsigned short* z1T = (unsigned short*)d_ws;           // 12.8M bf16 (head-major)
    unsigned short* h1 = (unsigned short*)((float*)d_ws + 6400000);  // 12.8M bf16
    float* as1 = (float*)d_ws + 12800000;                  // 400,000 (transposed [8][50000])
    float* ad1 = as1 + 400000;                             // 400,000 (transposed [8][50000])
    unsigned short* z2b = (unsigned short*)(ad1 + 400000); // 1.6M bf16
    float* as2 = ad1 + 400000 + 800000;                    // 50,000
    float* ad2 = as2 + 50000;                              // 50,000
    short8* W1frag = (short8*)(ad2 + 50000);               // 8192 * 16 B
    short8* W2frag = W1frag + 8192;                        // 1024 * 16 B
    int* deg       = (int*)(ad2 + 50000) + 36864;          // 50,000
    int* row_start = deg + 50000;                          // 50,001
    int* csr_src   = row_start + 50001;                    // 850,000
    int* row_local = csr_src + 850000;                     // 50,000
    int* bsum      = row_local + 50000;                    // 256
    // pos aliases z2b: written by wprep_hist, consumed by gemm1_scatter, dead before gemm2
    unsigned short* pos = (unsigned short*)z2b;            // 850,000 u16
    // xbf aliases h1: written by wprep_hist, consumed by gemm1_scatter, dead before agg1
    short8* xbf = (short8*)h1;                             // 1,600,000 short8 = 25.6 MB

    hipMemsetAsync(deg, 0, (size_t)50000 * 4, stream);

    // ---- weight prep + x->bf16 + histogram (+ per-edge rank) + scan ----
    wprep_hist_k<<<36 + XCONV_BLKS + SCAT_BLKS, 256, 0, stream>>>(
        W1, W2, W1frag, W2frag, x, xbf, ei, deg, pos);
    scan_part_k<<<NSCAN_BLK, 256, 0, stream>>>(deg, row_local, bsum);
    scan_fix_k<<<NSCAN_BLK, 256, 0, stream>>>(row_local, bsum, row_start);

    // ---- layer 1 (gemm1 fused with atomic-free CSR scatter) ----
    gemm1_scatter_k<<<GEMM1_BLKS + SCAT_BLKS, 256, 0, stream>>>(
        xbf, W1frag, av1, bv1, z1T, as1, ad1, ei, row_start, pos, csr_src);
    agg1_csr_k<<<AGG1_BLKS, 256, 0, stream>>>(row_start, csr_src, z1T, as1, ad1, b1, h1);

    // ---- layer 2 ----
    gemm2_mfma_k<<<(NNODES + 63) / 64, 256, 0, stream>>>(h1, W2frag, av2, bv2, z2b, as2, ad2);
    agg2_csr_k<<<NDBLK, 256, 0, stream>>>(row_start, csr_src, z2b, as2, ad2, b2, out);
}

// Round 5
// 282.571 us; speedup vs baseline: 1.2823x; 1.0893x over previous
//
#include <hip/hip_runtime.h>

#define NNODES 50000
#define NFEAT 256
#define NHID 32
#define NHEADS 8
#define NCLASSES 32
#define NEDGES 800000
#define ETOT (NEDGES + NNODES)   // 850000 with self loops
#define NSCAN_BLK 196            // ceil(50000/256)
#define GEMM1_BLKS 782           // ceil(50000/64)
#define SCAT_BLKS 3321           // ceil(850000/256)

typedef __attribute__((ext_vector_type(8))) short short8;
typedef __attribute__((ext_vector_type(4))) float f32x4;

__device__ __forceinline__ void get_edge(const int* __restrict__ ei, int e,
                                         int& s, int& d) {
    if (e < NEDGES) { s = ei[e]; d = ei[NEDGES + e]; }
    else            { s = e - NEDGES; d = s; }
}
__device__ __forceinline__ float lrelu(float x) { return x > 0.f ? x : 0.2f * x; }
__device__ __forceinline__ unsigned short f2bf(float f) {   // RNE
    unsigned u = __float_as_uint(f);
    unsigned r = u + 0x7fffu + ((u >> 16) & 1u);
    return (unsigned short)(r >> 16);
}
__device__ __forceinline__ float bflo(unsigned u) { return __uint_as_float(u << 16); }
__device__ __forceinline__ float bfhi(unsigned u) { return __uint_as_float(u & 0xffff0000u); }

// ---------- fused: weight prep (blocks 0..35) + degree histogram + rank (rest) ----------
// pos[e] = within-dst arrival rank, from the SAME atomicAdd that builds the histogram.
__global__ void wprep_hist_k(const float* __restrict__ W1, const float* __restrict__ W2,
                             short8* __restrict__ W1frag, short8* __restrict__ W2frag,
                             const int* __restrict__ ei, int* __restrict__ deg,
                             unsigned short* __restrict__ pos) {
    if (blockIdx.x < 36) {
        int idx = blockIdx.x * 256 + threadIdx.x;
        if (idx < 8192) {
            int kc = idx >> 10, r = idx & 1023;
            int nt = r >> 6, lane = r & 63;
            int l16 = lane & 15, quad = lane >> 4;
            int n = nt * 16 + l16, k0 = kc * 32 + quad * 8;
            short8 v;
#pragma unroll
            for (int j = 0; j < 8; ++j) v[j] = (short)f2bf(W1[(k0 + j) * 256 + n]);
            W1frag[idx] = v;
        } else if (idx < 8192 + 1024) {
            int g = idx - 8192;
            int kc = g >> 7, r = g & 127;
            int nt = r >> 6, lane = r & 63;
            int l16 = lane & 15, quad = lane >> 4;
            int n = nt * 16 + l16, k0 = kc * 32 + quad * 8;
            short8 v;
#pragma unroll
            for (int j = 0; j < 8; ++j) v[j] = (short)f2bf(W2[(k0 + j) * 32 + n]);
            W2frag[g] = v;
        }
    } else {
        int e = (blockIdx.x - 36) * 256 + threadIdx.x;
        if (e >= ETOT) return;
        int d = (e < NEDGES) ? ei[NEDGES + e] : (e - NEDGES);
        pos[e] = (unsigned short)atomicAdd(&deg[d], 1);
    }
}

// ---------- parallel scan, phase 1: per-block exclusive scan + block sums ----------
__global__ void scan_part_k(const int* __restrict__ deg, int* __restrict__ row_local,
                            int* __restrict__ bsum) {
    __shared__ int ws[4];
    int t = threadIdx.x, lane = t & 63, wid = t >> 6;
    int idx = blockIdx.x * 256 + t;
    int v = (idx < NNODES) ? deg[idx] : 0;
    int inc = v;
#pragma unroll
    for (int off = 1; off < 64; off <<= 1) {
        int u = __shfl_up(inc, off, 64);
        if (lane >= off) inc += u;
    }
    if (lane == 63) ws[wid] = inc;
    __syncthreads();
    int woff = 0;
#pragma unroll
    for (int j = 0; j < 4; ++j) woff += (j < wid) ? ws[j] : 0;
    if (idx < NNODES) row_local[idx] = woff + inc - v;
    if (t == 255) bsum[blockIdx.x] = woff + inc;
}

// ---------- scan phase 2+3 merged ----------
__global__ void scan_fix_k(const int* __restrict__ row_local, const int* __restrict__ bsum,
                           int* __restrict__ row_start) {
    __shared__ int ws[4];
    __shared__ int sboff;
    int t = threadIdx.x, lane = t & 63, wid = t >> 6;
    int v = (t < NSCAN_BLK) ? bsum[t] : 0;
    int inc = v;
#pragma unroll
    for (int off = 1; off < 64; off <<= 1) {
        int u = __shfl_up(inc, off, 64);
        if (lane >= off) inc += u;
    }
    if (lane == 63) ws[wid] = inc;
    __syncthreads();
    int woff = 0;
#pragma unroll
    for (int j = 0; j < 4; ++j) woff += (j < wid) ? ws[j] : 0;
    if (t == blockIdx.x) sboff = woff + inc - v;
    __syncthreads();
    int idx = blockIdx.x * 256 + t;
    if (idx < NNODES) row_start[idx] = row_local[idx] + sboff;
    if (idx == 0) row_start[NNODES] = ETOT;
}

// ---------- fused GEMM1 (MFMA bf16, barrier-free) + attn1 epilogue + atomic-free scatter ----------
// x read as f32, converted once in the prologue into 8 short8 regs (no per-kc loads,
// no LDS, no barriers: W fragments are identical wave-broadcasts -> L1/L2-hot).
// z1 row-major [node][256]; as/ad row-major [node][8] (proven agg1 layout).
__global__ __launch_bounds__(256) void gemm1_scatter_k(
        const float* __restrict__ x, const short8* __restrict__ Wfrag,
        const float* __restrict__ av, const float* __restrict__ bv,
        unsigned short* __restrict__ z1, float* __restrict__ as_, float* __restrict__ ad_,
        const int* __restrict__ ei, const int* __restrict__ row_start,
        const unsigned short* __restrict__ pos, int* __restrict__ csr_src) {
    if (blockIdx.x >= GEMM1_BLKS) {
        int e = (blockIdx.x - GEMM1_BLKS) * 256 + threadIdx.x;
        if (e >= ETOT) return;
        int s, d;
        get_edge(ei, e, s, d);
        csr_src[row_start[d] + (int)pos[e]] = s;    // no atomic: rank precomputed
        return;
    }
    int t = threadIdx.x;
    int w = t >> 6, lane = t & 63;
    int quad = lane >> 4, l16 = lane & 15;
    int mA = blockIdx.x * 64 + w * 16 + l16;
    int mAl = min(mA, NNODES - 1);

    // prologue: load this lane's f32 x slices (16B chunks), convert to bf16 regs
    const float4* xp = (const float4*)(x + (size_t)mAl * 256);
    short8 xreg[8];
#pragma unroll
    for (int kc = 0; kc < 8; ++kc) {
        float4 a0 = xp[kc * 8 + quad * 2];
        float4 a1 = xp[kc * 8 + quad * 2 + 1];
        short8 af;
        af[0] = (short)f2bf(a0.x); af[1] = (short)f2bf(a0.y);
        af[2] = (short)f2bf(a0.z); af[3] = (short)f2bf(a0.w);
        af[4] = (short)f2bf(a1.x); af[5] = (short)f2bf(a1.y);
        af[6] = (short)f2bf(a1.z); af[7] = (short)f2bf(a1.w);
        xreg[kc] = af;
    }

    f32x4 acc[16];
#pragma unroll
    for (int nt = 0; nt < 16; ++nt) acc[nt] = (f32x4){0.f, 0.f, 0.f, 0.f};

#pragma unroll
    for (int kc = 0; kc < 8; ++kc) {
        short8 af = xreg[kc];
#pragma unroll
        for (int nt = 0; nt < 16; ++nt) {
            short8 bf8 = Wfrag[kc * 1024 + nt * 64 + lane];
            acc[nt] = __builtin_amdgcn_mfma_f32_16x16x32_bf16(af, bf8, acc[nt], 0, 0, 0);
        }
    }
    int mrow0 = blockIdx.x * 64 + w * 16 + quad * 4;
#pragma unroll
    for (int nt = 0; nt < 16; ++nt) {
        int n = nt * 16 + l16;
#pragma unroll
        for (int r = 0; r < 4; ++r) {
            int mr = mrow0 + r;
            if (mr < NNODES) z1[(size_t)mr * 256 + n] = f2bf(acc[nt][r]);
        }
    }
#pragma unroll
    for (int h = 0; h < 8; ++h) {
        float av0 = av[(2 * h) * 16 + l16], av1v = av[(2 * h + 1) * 16 + l16];
        float bv0 = bv[(2 * h) * 16 + l16], bv1v = bv[(2 * h + 1) * 16 + l16];
#pragma unroll
        for (int r = 0; r < 4; ++r) {
            float pa = acc[2 * h][r] * av0 + acc[2 * h + 1][r] * av1v;
            float pb = acc[2 * h][r] * bv0 + acc[2 * h + 1][r] * bv1v;
#pragma unroll
            for (int off = 1; off < 16; off <<= 1) {
                pa += __shfl_xor(pa, off, 64);
                pb += __shfl_xor(pb, off, 64);
            }
            int mr = mrow0 + r;
            if (l16 == 0 && mr < NNODES) { as_[mr * 8 + h] = pa; ad_[mr * 8 + h] = pb; }
        }
    }
}

// ---------- GEMM2 (MFMA bf16) + fused attn2 epilogue; z2 stored bf16 ----------
__global__ __launch_bounds__(256) void gemm2_mfma_k(
        const unsigned short* __restrict__ h1, const short8* __restrict__ Wfrag,
        const float* __restrict__ av, const float* __restrict__ bv,
        unsigned short* __restrict__ z2b, float* __restrict__ as_, float* __restrict__ ad_) {
    int w = threadIdx.x >> 6, lane = threadIdx.x & 63;
    int quad = lane >> 4, l16 = lane & 15;
    int mA = blockIdx.x * 64 + w * 16 + l16;
    int mAl = min(mA, NNODES - 1);

    f32x4 acc[2];
    acc[0] = (f32x4){0.f, 0.f, 0.f, 0.f};
    acc[1] = (f32x4){0.f, 0.f, 0.f, 0.f};
    for (int kc = 0; kc < 8; ++kc) {
        int k0 = kc * 32 + quad * 8;
        short8 af = *(const short8*)(h1 + (size_t)mAl * 256 + k0);
#pragma unroll
        for (int nt = 0; nt < 2; ++nt) {
            short8 bf8 = Wfrag[kc * 128 + nt * 64 + lane];
            acc[nt] = __builtin_amdgcn_mfma_f32_16x16x32_bf16(af, bf8, acc[nt], 0, 0, 0);
        }
    }
    int mrow0 = blockIdx.x * 64 + w * 16 + quad * 4;
    float av0 = av[l16], av1v = av[16 + l16];
    float bv0 = bv[l16], bv1v = bv[16 + l16];
#pragma unroll
    for (int r = 0; r < 4; ++r) {
        int mr = mrow0 + r;
        float pa = acc[0][r] * av0 + acc[1][r] * av1v;
        float pb = acc[0][r] * bv0 + acc[1][r] * bv1v;
#pragma unroll
        for (int off = 1; off < 16; off <<= 1) {
            pa += __shfl_xor(pa, off, 64);
            pb += __shfl_xor(pb, off, 64);
        }
        if (mr < NNODES) {
            z2b[(size_t)mr * 32 + l16] = f2bf(acc[0][r]);
            z2b[(size_t)mr * 32 + 16 + l16] = f2bf(acc[1][r]);
            if (l16 == 0) { as_[mr] = pa; ad_[mr] = pb; }
        }
    }
}

// ---------- layer-1 aggregation: one wave per dst (all 8 heads), masked strips, pipelined ----------
// PROVEN round-0 structure (72us, ~6.2 TB/s delivered = at roofline). Upgrades:
// (a) masked final strip replaces the serial tail loop; (b) 2-deep pipeline -
// next strip's csr load + as-gather + exp overlap the current strip's z-load batch.
__global__ void agg1_csr_k(const int* __restrict__ row_start, const int* __restrict__ csr_src,
                           const unsigned short* __restrict__ z, const float* __restrict__ as_,
                           const float* __restrict__ ad_, const float* __restrict__ b,
                           unsigned short* __restrict__ h1) {
    int wv = threadIdx.x >> 6, lane = threadIdx.x & 63;
    int d = blockIdx.x * 4 + wv;
    int h = lane >> 3;
    int c0 = lane * 4;
    int e8 = lane & 7;
    float adh = ad_[d * 8 + h];
    int beg = row_start[d], end = row_start[d + 1];
    float sum = 0.f, a0 = 0.f, a1 = 0.f, a2 = 0.f, a3 = 0.f;

    // pipeline prologue: strip-0 index + weight (masked)
    int idx = beg + e8;
    int sv = csr_src[idx < end ? idx : end - 1];
    float myw = __expf(lrelu(as_[sv * 8 + h] + adh));
    myw = (idx < end) ? myw : 0.f;

    for (int i = beg; i < end; i += 8) {
        // prefetch strip n+1 (clamped; overlaps current z-load batch)
        int idx2 = i + 8 + e8;
        int sv2 = csr_src[idx2 < end ? idx2 : end - 1];
        float myw2 = __expf(lrelu(as_[sv2 * 8 + h] + adh));
        myw2 = (idx2 < end) ? myw2 : 0.f;

        int se[8];
        float we[8];
#pragma unroll
        for (int e = 0; e < 8; ++e) {
            se[e] = __shfl(sv, e, 64);
            we[e] = __shfl(myw, (lane & 56) | e, 64);
        }
        uint2 q[8];
#pragma unroll
        for (int e = 0; e < 8; ++e)
            q[e] = *(const uint2*)(z + (size_t)se[e] * 256 + c0);
#pragma unroll
        for (int e = 0; e < 8; ++e) {
            float wgt = we[e];
            sum += wgt;
            a0 += wgt * bflo(q[e].x);
            a1 += wgt * bfhi(q[e].x);
            a2 += wgt * bflo(q[e].y);
            a3 += wgt * bfhi(q[e].y);
        }
        sv = sv2;
        myw = myw2;
    }
    float inv = 1.f / sum;
    float o0 = a0 * inv + b[c0 + 0];
    float o1 = a1 * inv + b[c0 + 1];
    float o2 = a2 * inv + b[c0 + 2];
    float o3 = a3 * inv + b[c0 + 3];
    o0 = o0 > 0.f ? o0 : expm1f(o0);
    o1 = o1 > 0.f ? o1 : expm1f(o1);
    o2 = o2 > 0.f ? o2 : expm1f(o2);
    o3 = o3 > 0.f ? o3 : expm1f(o3);
    uint2 pk;
    pk.x = (unsigned)f2bf(o0) | ((unsigned)f2bf(o1) << 16);
    pk.y = (unsigned)f2bf(o2) | ((unsigned)f2bf(o3) << 16);
    *(uint2*)(h1 + (size_t)d * 256 + c0) = pk;
}

// ---------- fused layer-2 aggregation + bias: 16 lanes/dst, 2 bf16 ch/lane (round-0 proven) ----------
__global__ void agg2_csr_k(const int* __restrict__ row_start, const int* __restrict__ csr_src,
                           const unsigned short* __restrict__ z2b, const float* __restrict__ as_,
                           const float* __restrict__ ad_, const float* __restrict__ b,
                           float* __restrict__ out) {
    int g = blockIdx.x * 16 + (threadIdx.x >> 4);   // 16 dsts per 256-thr block
    int l = threadIdx.x & 15;
    int lane = threadIdx.x & 63;
    int c0 = l * 2;
    int beg = row_start[g], end = row_start[g + 1];
    float adn = ad_[g];
    int e8 = l & 7;
    int gb = lane & 48;                             // 16-lane group base within wave
    float sum = 0.f, a0 = 0.f, a1 = 0.f;
    int i = beg;
    for (; i + 8 <= end; i += 8) {
        int sv = csr_src[i + e8];
        float myw = __expf(lrelu(as_[sv] + adn));
        int se[8];
        float we[8];
#pragma unroll
        for (int e = 0; e < 8; ++e) {
            se[e] = __shfl(sv, gb | e, 64);
            we[e] = __shfl(myw, gb | (8 | e), 64);
        }
        unsigned q[8];
#pragma unroll
        for (int e = 0; e < 8; ++e)
            q[e] = *(const unsigned*)(z2b + (size_t)se[e] * 32 + c0);
#pragma unroll
        for (int e = 0; e < 8; ++e) {
            float wgt = we[e];
            sum += wgt;
            a0 += wgt * bflo(q[e]);
            a1 += wgt * bfhi(q[e]);
        }
    }
    for (; i < end; ++i) {
        int s = csr_src[i];
        float wgt = __expf(lrelu(as_[s] + adn));
        unsigned q = *(const unsigned*)(z2b + (size_t)s * 32 + c0);
        sum += wgt;
        a0 += wgt * bflo(q);
        a1 += wgt * bfhi(q);
    }
    float inv = 1.f / sum;
    float2 o;
    o.x = a0 * inv + b[c0];
    o.y = a1 * inv + b[c0 + 1];
    *(float2*)(out + (size_t)g * 32 + c0) = o;
}

extern "C" void kernel_launch(void* const* d_in, const int* in_sizes, int n_in,
                              void* d_out, int out_size, void* d_ws, size_t ws_size,
                              hipStream_t stream) {
    const float* x   = (const float*)d_in[0];
    const int*   ei  = (const int*)d_in[1];
    const float* W1  = (const float*)d_in[2];
    const float* av1 = (const float*)d_in[3];
    const float* bv1 = (const float*)d_in[4];
    const float* b1  = (const float*)d_in[5];
    const float* W2  = (const float*)d_in[6];
    const float* av2 = (const float*)d_in[7];
    const float* bv2 = (const float*)d_in[8];
    const float* b2  = (const float*)d_in[9];
    float* out = (float*)d_out;

    // workspace layout (4-byte units)
    unsigned short* z1 = (unsigned short*)d_ws;            // 12.8M bf16 [node][256]
    unsigned short* h1 = (unsigned short*)((float*)d_ws + 6400000);  // 12.8M bf16
    float* as1 = (float*)d_ws + 12800000;                  // 400,000 [node][8]
    float* ad1 = as1 + 400000;                             // 400,000 [node][8]
    unsigned short* z2b = (unsigned short*)(ad1 + 400000); // 1.6M bf16
    float* as2 = ad1 + 400000 + 800000;                    // 50,000
    float* ad2 = as2 + 50000;                              // 50,000
    short8* W1frag = (short8*)(ad2 + 50000);               // 8192 * 16 B
    short8* W2frag = W1frag + 8192;                        // 1024 * 16 B
    int* deg       = (int*)(ad2 + 50000) + 36864;          // 50,000
    int* row_start = deg + 50000;                          // 50,001
    int* csr_src   = row_start + 50001;                    // 850,000
    int* row_local = csr_src + 850000;                     // 50,000
    int* bsum      = row_local + 50000;                    // 256
    // pos aliases z2b: written by wprep_hist, consumed by gemm1_scatter, dead before gemm2
    unsigned short* pos = (unsigned short*)z2b;            // 850,000 u16

    hipMemsetAsync(deg, 0, (size_t)50000 * 4, stream);

    // ---- weight prep + histogram (+ per-edge rank) + scan ----
    wprep_hist_k<<<36 + SCAT_BLKS, 256, 0, stream>>>(W1, W2, W1frag, W2frag, ei, deg, pos);
    scan_part_k<<<NSCAN_BLK, 256, 0, stream>>>(deg, row_local, bsum);
    scan_fix_k<<<NSCAN_BLK, 256, 0, stream>>>(row_local, bsum, row_start);

    // ---- layer 1 (gemm1 fused with atomic-free CSR scatter) ----
    gemm1_scatter_k<<<GEMM1_BLKS + SCAT_BLKS, 256, 0, stream>>>(
        x, W1frag, av1, bv1, z1, as1, ad1, ei, row_start, pos, csr_src);
    agg1_csr_k<<<(NNODES + 3) / 4, 256, 0, stream>>>(row_start, csr_src, z1, as1, ad1, b1, h1);

    // ---- layer 2 ----
    gemm2_mfma_k<<<(NNODES + 63) / 64, 256, 0, stream>>>(h1, W2frag, av2, bv2, z2b, as2, ad2);
    agg2_csr_k<<<NNODES / 16, 256, 0, stream>>>(row_start, csr_src, z2b, as2, ad2, b2, out);
}